// Round 6
// baseline (367.972 us; speedup 1.0000x reference)
//
#include <hip/hip_runtime.h>
#include <hip/hip_bf16.h>
#include <math.h>

#define NTOK 4096
#define DIN  1024
#define H1D  2048
#define H2D  1024
#define NE   8
#define KSEL 2

constexpr int BK = 32;

typedef __attribute__((ext_vector_type(8))) __bf16 bf16x8;
typedef __attribute__((ext_vector_type(4))) float  f32x4;

__device__ __forceinline__ ushort f2bf(float f) {
    union { float f; unsigned u; } c; c.f = f;
    unsigned u = c.u;
    return (ushort)((u + 0x7fffu + ((u >> 16) & 1u)) >> 16);   // RNE
}

// ---------------------------------------------------------------------------
__global__ void zero_counts(int* counts) {
    if (threadIdx.x < NE) counts[threadIdx.x] = 0;
}

__global__ void convert_x(const float* __restrict__ x, ushort* __restrict__ xbf) {
    int i = (blockIdx.x * blockDim.x + threadIdx.x) * 4;
    float4 v = *(const float4*)(x + i);
    ushort4 o;
    o.x = f2bf(v.x); o.y = f2bf(v.y); o.z = f2bf(v.z); o.w = f2bf(v.w);
    *(ushort4*)(xbf + i) = o;
}

// W[e][K][N] fp32 -> Wt[e][N][K] bf16.  Tile 64(k) x 128(n), 256 threads.
__global__ __launch_bounds__(256)
void transpose_cvt(const float* __restrict__ W, ushort* __restrict__ Wt,
                   int K, int N) {
    __shared__ float t[64][132];
    const int e  = blockIdx.z;
    const int n0 = blockIdx.x * 128;
    const int k0 = blockIdx.y * 64;
    const int tid = threadIdx.x;

    const float* src = W + ((size_t)e * K + k0) * N + n0;
#pragma unroll
    for (int p = 0; p < 8; ++p) {
        int c  = tid + p * 256;
        int kk = c >> 5;
        int nn = (c & 31) * 4;
        float4 v = *(const float4*)(src + (size_t)kk * N + nn);
        t[kk][nn + 0] = v.x; t[kk][nn + 1] = v.y;
        t[kk][nn + 2] = v.z; t[kk][nn + 3] = v.w;
    }
    __syncthreads();

    const int n = tid >> 1;
    const int h = tid & 1;
    ushort outv[32];
#pragma unroll
    for (int j = 0; j < 32; ++j) outv[j] = f2bf(t[h * 32 + j][n]);
    ushort* dst = Wt + ((size_t)e * N + n0 + n) * K + k0 + h * 32;
#pragma unroll
    for (int q = 0; q < 4; ++q)
        *(uint4*)(dst + q * 8) = *(const uint4*)(outv + q * 8);
}

// ---------------------------------------------------------------------------
__global__ void topk_gate(const float* __restrict__ gates,
                          float* __restrict__ g_out,
                          int* __restrict__ counts,
                          int* __restrict__ bucket,
                          int* __restrict__ tke,
                          float* __restrict__ tkg,
                          float* __restrict__ ppart)
{
    int n = blockIdx.x * blockDim.x + threadIdx.x;
    if (n >= NTOK) return;

    ppart[n * 2 + 0] = 0.f;
    ppart[n * 2 + 1] = 0.f;

    float v[NE];
#pragma unroll
    for (int e = 0; e < NE; ++e) v[e] = gates[n * NE + e];

    int i1 = 0; float v1 = v[0];
#pragma unroll
    for (int e = 1; e < NE; ++e) if (v[e] > v1) { v1 = v[e]; i1 = e; }
    int i2 = -1; float v2 = -1e30f;
#pragma unroll
    for (int e = 0; e < NE; ++e) if (e != i1 && v[e] > v2) { v2 = v[e]; i2 = e; }

    float s = v1 + v2 + 1e-10f;
    float g1 = v1 / s, g2 = v2 / s;

#pragma unroll
    for (int e = 0; e < NE; ++e) {
        float gv = 0.f;
        if (e == i1) gv = g1;
        if (e == i2) gv = g2;
        g_out[n * NE + e] = gv;
    }
    tke[n * 2 + 0] = i1; tkg[n * 2 + 0] = g1;
    tke[n * 2 + 1] = i2; tkg[n * 2 + 1] = g2;

    int s1 = atomicAdd(&counts[i1], 1);
    bucket[i1 * NTOK + s1] = n * 2 + 0;
    int s2 = atomicAdd(&counts[i2], 1);
    bucket[i2 * NTOK + s2] = n * 2 + 1;
}

// ---------------------------------------------------------------------------
// Grouped bf16 MFMA GEMM, 256-row tiles, 512 threads / 8 waves, dbuf LDS,
// BK=32.  Wave grid WROWS x WCOLS; per-wave output (256/WROWS) x (BN_/WCOLS).
// Staging identical pattern to the verified 128^2 kernel: global_load_lds
// 16B/lane, linear LDS dest, XOR swizzle slot^=((line>>1)&3) via pre-permuted
// source.  Wave-bands with no valid rows skip fragment reads + MFMA (tail).
// Grid 1D: e = b&7 (expert pinned to XCD); idx=b>>3: tile=idx&15,
// col0=(idx>>4)*BN_.
// MODE 1: C = bf16(relu(acc+bias)).  MODE 2: fused relu+dot(W3) -> atomicAdd.
// ---------------------------------------------------------------------------
template<int SHIFT, int MODE, int BN_, int WROWS, int WCOLS>
__global__ __launch_bounds__(512, 2)
void moe_gemm(const ushort* __restrict__ Abf, int lda,
              const ushort* __restrict__ Wt,    // [NE][N][K] bf16
              const float* __restrict__ bias,   // [NE][N]
              int N,
              const float* __restrict__ W3,     // MODE2: [NE][H2D]
              ushort* __restrict__ Cbf,         // MODE1: [NTOK*KSEL][N]
              float* __restrict__ ppart,        // MODE2: [NTOK*KSEL]
              const int* __restrict__ bucket,
              const int* __restrict__ counts,
              int K)
{
    constexpr int BM_  = 256;
    constexpr int MREP = BM_ / WROWS / 16;      // 8 (L1) / 4 (L2)
    constexpr int NREP = BN_ / WCOLS / 16;      // 4
    constexpr int ACH  = BM_ * 4 / 512;         // A chunks per thread (2)
    constexpr int BCH  = BN_ * 4 / 512;         // B chunks per thread (2 or 1)

    const int b    = blockIdx.x;
    const int e    = b & 7;
    const int idx  = b >> 3;
    const int tile = idx & 15;
    const int col0 = (idx >> 4) * BN_;

    const int cnt  = counts[e];
    const int row0 = tile * BM_;
    if (row0 >= cnt) return;

    __shared__ int rowmap[BM_];
    __shared__ __align__(16) ushort smA[2][BM_ * BK];
    __shared__ __align__(16) ushort smB[2][BN_ * BK];

    const int tid = threadIdx.x;
    if (tid < BM_) {
        int r = row0 + tid;
        rowmap[tid] = (r < cnt) ? bucket[e * NTOK + r] : -1;
    }
    __syncthreads();

    const int lane = tid & 63;
    const int wid  = tid >> 6;
    const int wm   = wid / WCOLS;
    const int wn   = wid % WCOLS;
    const bool wactive = (row0 + wm * (BM_ / WROWS)) < cnt;

    const ushort* aSrc[ACH];
    int aDst[ACH];
#pragma unroll
    for (int i = 0; i < ACH; ++i) {
        int c    = wid * 64 + lane + i * 512;
        int line = c >> 2;
        int slot = c & 3;
        int sch  = slot ^ ((line >> 1) & 3);
        aDst[i] = c * 8;
        int entry = rowmap[line];
        int arow  = (entry >= 0) ? (entry >> SHIFT) : 0;
        aSrc[i] = Abf + (size_t)arow * lda + sch * 8;
    }
    const ushort* bSrc[BCH];
    int bDst[BCH];
#pragma unroll
    for (int i = 0; i < BCH; ++i) {
        int c    = wid * 64 + lane + i * 512;
        int line = c >> 2;
        int slot = c & 3;
        int sch  = slot ^ ((line >> 1) & 3);
        bDst[i] = c * 8;
        bSrc[i] = Wt + ((size_t)e * N + col0 + line) * K + sch * 8;
    }

    f32x4 acc[MREP][NREP];
#pragma unroll
    for (int i = 0; i < MREP; ++i)
#pragma unroll
        for (int j = 0; j < NREP; ++j)
            acc[i][j] = (f32x4){0.f, 0.f, 0.f, 0.f};

    auto stage = [&](int buf, int k0) {
#pragma unroll
        for (int i = 0; i < ACH; ++i)
            __builtin_amdgcn_global_load_lds(
                (const __attribute__((address_space(1))) unsigned*)(aSrc[i] + k0),
                (__attribute__((address_space(3))) unsigned*)&smA[buf][aDst[i]],
                16, 0, 0);
#pragma unroll
        for (int i = 0; i < BCH; ++i)
            __builtin_amdgcn_global_load_lds(
                (const __attribute__((address_space(1))) unsigned*)(bSrc[i] + k0),
                (__attribute__((address_space(3))) unsigned*)&smB[buf][bDst[i]],
                16, 0, 0);
    };

    auto compute = [&](int buf) {
        if (!wactive) return;    // tail band: no valid rows for this wave
        bf16x8 a[MREP], bfr[NREP];
#pragma unroll
        for (int mi = 0; mi < MREP; ++mi) {
            int row  = wm * (BM_ / WROWS) + mi * 16 + (lane & 15);
            int slot = (lane >> 4) ^ ((row >> 1) & 3);
            a[mi] = *(const bf16x8*)&smA[buf][row * 32 + slot * 8];
        }
#pragma unroll
        for (int ni = 0; ni < NREP; ++ni) {
            int col  = wn * (BN_ / WCOLS) + ni * 16 + (lane & 15);
            int slot = (lane >> 4) ^ ((col >> 1) & 3);
            bfr[ni] = *(const bf16x8*)&smB[buf][col * 32 + slot * 8];
        }
#pragma unroll
        for (int mi = 0; mi < MREP; ++mi)
#pragma unroll
            for (int ni = 0; ni < NREP; ++ni)
                acc[mi][ni] = __builtin_amdgcn_mfma_f32_16x16x32_bf16(
                    a[mi], bfr[ni], acc[mi][ni], 0, 0, 0);
    };

    const int nt = K / BK;
    stage(0, 0);
    __syncthreads();
    for (int t = 0; t < nt; ++t) {
        int cur = t & 1;
        if (t + 1 < nt) stage(cur ^ 1, (t + 1) * BK);
        compute(cur);
        __syncthreads();
    }

    if (!wactive) return;

    // ---- epilogue. C/D layout: col=lane&15, row=(lane>>4)*4+reg
    if (MODE == 1) {
        float bb[NREP];
#pragma unroll
        for (int ni = 0; ni < NREP; ++ni)
            bb[ni] = bias[e * N + col0 + wn * (BN_ / WCOLS) + ni * 16 + (lane & 15)];
#pragma unroll
        for (int mi = 0; mi < MREP; ++mi) {
#pragma unroll
            for (int r = 0; r < 4; ++r) {
                int rt = wm * (BM_ / WROWS) + mi * 16 + (lane >> 4) * 4 + r;
                int entry = rowmap[rt];
                if (entry < 0) continue;
                ushort* crow = Cbf + (size_t)entry * N + col0;
#pragma unroll
                for (int ni = 0; ni < NREP; ++ni) {
                    float val = fmaxf(acc[mi][ni][r] + bb[ni], 0.f);
                    crow[wn * (BN_ / WCOLS) + ni * 16 + (lane & 15)] = f2bf(val);
                }
            }
        }
    } else {
        float bb[NREP], w3l[NREP];
#pragma unroll
        for (int ni = 0; ni < NREP; ++ni) {
            int cg = col0 + wn * (BN_ / WCOLS) + ni * 16 + (lane & 15);
            bb[ni]  = bias[e * N + cg];
            w3l[ni] = W3[e * H2D + cg];
        }
#pragma unroll
        for (int mi = 0; mi < MREP; ++mi) {
#pragma unroll
            for (int r = 0; r < 4; ++r) {
                float s = 0.f;
#pragma unroll
                for (int ni = 0; ni < NREP; ++ni)
                    s += fmaxf(acc[mi][ni][r] + bb[ni], 0.f) * w3l[ni];
#pragma unroll
                for (int off = 1; off < 16; off <<= 1)
                    s += __shfl_xor(s, off, 16);
                if ((lane & 15) == 0) {
                    int rt = wm * (BM_ / WROWS) + mi * 16 + (lane >> 4) * 4 + r;
                    int entry = rowmap[rt];
                    if (entry >= 0) atomicAdd(&ppart[entry], s);
                }
            }
        }
    }
}

// ---------------------------------------------------------------------------
__global__ void finalize(const float* __restrict__ pp, const float* __restrict__ b3,
                         const int* __restrict__ tke, const float* __restrict__ tkg,
                         float* __restrict__ pred) {
    int n = blockIdx.x * blockDim.x + threadIdx.x;
    if (n >= NTOK) return;
    float r = 0.f;
#pragma unroll
    for (int k = 0; k < KSEL; ++k) {
        int p = n * 2 + k;
        int ee = tke[p];
        float y = 1.f / (1.f + expf(-(pp[p] + b3[ee])));
        r += tkg[p] * y;
    }
    pred[n] = r;
}

// ---------------------------------------------------------------------------
extern "C" void kernel_launch(void* const* d_in, const int* in_sizes, int n_in,
                              void* d_out, int out_size, void* d_ws, size_t ws_size,
                              hipStream_t stream)
{
    const float* x     = (const float*)d_in[0];
    const float* gates = (const float*)d_in[1];
    const float* W1    = (const float*)d_in[2];
    const float* b1    = (const float*)d_in[3];
    const float* W2    = (const float*)d_in[4];
    const float* b2    = (const float*)d_in[5];
    const float* W3    = (const float*)d_in[6];
    const float* b3    = (const float*)d_in[7];

    float* out  = (float*)d_out;
    float* pred = out;
    float* gout = out + NTOK;

    // ws (~73 MB): hdr 1MB | xbf 8MB | h1bf 32MB | Wtbuf 32MB (shared W1t/W2t)
    char* ws = (char*)d_ws;
    int*    counts = (int*)(ws);
    int*    bucket = (int*)(ws + 4096);
    int*    tke    = (int*)(ws + 4096 + 131072);
    float*  tkg    = (float*)(ws + 4096 + 131072 + 32768);
    float*  ppart  = (float*)(ws + 4096 + 131072 + 65536);
    ushort* xbf    = (ushort*)(ws + (1 << 20));
    ushort* h1bf   = (ushort*)(ws + (1 << 20) + (size_t)NTOK * DIN * 2);
    ushort* wtbuf  = (ushort*)(ws + (1 << 20) + (size_t)NTOK * DIN * 2
                                  + (size_t)NTOK * KSEL * H1D * 2);

    zero_counts<<<1, 64, 0, stream>>>(counts);
    topk_gate<<<NTOK / 256, 256, 0, stream>>>(gates, gout, counts, bucket,
                                              tke, tkg, ppart);
    convert_x<<<NTOK * DIN / 4 / 256, 256, 0, stream>>>(x, xbf);

    // W1 [e][1024][2048] -> Wt [e][2048][1024]
    transpose_cvt<<<dim3(H1D / 128, DIN / 64, NE), 256, 0, stream>>>(
        W1, wtbuf, DIN, H1D);
    // L1: 256x256 tiles, 8 waves 2x4, per-wave 128x64
    moe_gemm<1, 1, 256, 2, 4><<<NE * 16 * (H1D / 256), 512, 0, stream>>>(
        xbf, DIN, wtbuf, b1, H1D, nullptr, h1bf, nullptr, bucket, counts, DIN);

    // W2 [e][2048][1024] -> Wt [e][1024][2048]
    transpose_cvt<<<dim3(H2D / 128, H1D / 64, NE), 256, 0, stream>>>(
        W2, wtbuf, H1D, H2D);
    // L2: 256x128 tiles, 8 waves 4x2, per-wave 64x64 (grid stays 1024 -> CUs full)
    moe_gemm<0, 2, 128, 4, 2><<<NE * 16 * (H2D / 128), 512, 0, stream>>>(
        h1bf, H1D, wtbuf, b2, H2D, W3, nullptr, ppart, bucket, counts, H1D);

    finalize<<<NTOK / 256, 256, 0, stream>>>(ppart, b3, tke, tkg, pred);
}

// Round 7
// 322.303 us; speedup vs baseline: 1.1417x; 1.1417x over previous
//
#include <hip/hip_runtime.h>
#include <hip/hip_bf16.h>
#include <math.h>

#define NTOK 4096
#define DIN  1024
#define H1D  2048
#define H2D  1024
#define NE   8
#define KSEL 2

constexpr int BM = 128, BN = 128, BK = 32;
constexpr int MAX_TILES = NTOK / BM;  // 32

typedef __attribute__((ext_vector_type(8))) __bf16 bf16x8;
typedef __attribute__((ext_vector_type(4))) float  f32x4;

__device__ __forceinline__ ushort f2bf(float f) {
    union { float f; unsigned u; } c; c.f = f;
    unsigned u = c.u;
    return (ushort)((u + 0x7fffu + ((u >> 16) & 1u)) >> 16);   // RNE
}

// ---------------------------------------------------------------------------
// Transpose+convert one 128(k) x 64(n) tile: W[e][K][N] fp32 -> Wt[e][N][K] bf16.
// Reads float4-coalesced (256B per 16-lane group); writes 256B contiguous per
// 16-lane group (16B x 16 lanes along k). LDS [128][65] (4-way read conflicts,
// acceptable — global write BW is the limiter).
// ---------------------------------------------------------------------------
__device__ __forceinline__ void transpose_tile(const float* __restrict__ W,
                                               ushort* __restrict__ Wt,
                                               int K, int N, int e, int k0, int n0,
                                               int tid, float (*t)[65]) {
    const float* src = W + ((size_t)e * K + k0) * N + n0;
#pragma unroll
    for (int p = 0; p < 8; ++p) {
        int c  = tid + p * 256;          // 0..2047 float4 chunks
        int kk = c >> 4;                 // 0..127
        int nn = (c & 15) * 4;           // 0..60
        float4 v = *(const float4*)(src + (size_t)kk * N + nn);
        t[kk][nn + 0] = v.x; t[kk][nn + 1] = v.y;
        t[kk][nn + 2] = v.z; t[kk][nn + 3] = v.w;
    }
    __syncthreads();
#pragma unroll
    for (int p = 0; p < 4; ++p) {
        int c  = tid + p * 256;          // 0..1023 16B out-chunks
        int n  = c >> 4;                 // 0..63
        int ks = c & 15;                 // k-segment (8 elems)
        ushort ov[8];
#pragma unroll
        for (int j = 0; j < 8; ++j) ov[j] = f2bf(t[ks * 8 + j][n]);
        *(uint4*)(Wt + ((size_t)e * N + n0 + n) * K + k0 + ks * 8)
            = *(const uint4*)ov;
    }
}

// prep1: zero counts + convert x -> bf16 + transpose W1 -> W1t.
// blocks 0..2047: x (8 floats/thread). blocks 2048..4095: W1 tiles.
__global__ __launch_bounds__(256)
void prep1(const float* __restrict__ x, ushort* __restrict__ xbf,
           const float* __restrict__ W1, ushort* __restrict__ W1t,
           int* __restrict__ counts) {
    __shared__ float t[128][65];
    const int bid = blockIdx.x;
    const int tid = threadIdx.x;
    if (bid == 0 && tid < NE) counts[tid] = 0;
    if (bid < 2048) {
        size_t i = ((size_t)bid * 256 + tid) * 8;
        float4 v0 = *(const float4*)(x + i);
        float4 v1 = *(const float4*)(x + i + 4);
        ushort o[8] = {f2bf(v0.x), f2bf(v0.y), f2bf(v0.z), f2bf(v0.w),
                       f2bf(v1.x), f2bf(v1.y), f2bf(v1.z), f2bf(v1.w)};
        *(uint4*)(xbf + i) = *(const uint4*)o;
    } else {
        int tb = bid - 2048;             // W1: K=1024 (8 kb), N=2048 (32 nb)
        int n0 = (tb & 31) * 64;
        int k0 = ((tb >> 5) & 7) * 128;
        int e  = tb >> 8;
        transpose_tile(W1, W1t, DIN, H1D, e, k0, n0, tid, t);
    }
}

// prep2: transpose W2 -> W2t (runs after GEMM1; shares the wt buffer).
__global__ __launch_bounds__(256)
void prep2(const float* __restrict__ W2, ushort* __restrict__ W2t) {
    __shared__ float t[128][65];
    const int tb  = blockIdx.x;          // W2: K=2048 (16 kb), N=1024 (16 nb)
    const int n0  = (tb & 15) * 64;
    const int k0  = ((tb >> 4) & 15) * 128;
    const int e   = tb >> 8;
    transpose_tile(W2, W2t, H1D, H2D, e, k0, n0, threadIdx.x, t);
}

// ---------------------------------------------------------------------------
__global__ void topk_gate(const float* __restrict__ gates,
                          float* __restrict__ g_out,
                          int* __restrict__ counts,
                          int* __restrict__ bucket,
                          int* __restrict__ tke,
                          float* __restrict__ tkg,
                          float* __restrict__ ppart)
{
    int n = blockIdx.x * blockDim.x + threadIdx.x;
    if (n >= NTOK) return;

    ppart[n * 2 + 0] = 0.f;
    ppart[n * 2 + 1] = 0.f;

    float v[NE];
#pragma unroll
    for (int e = 0; e < NE; ++e) v[e] = gates[n * NE + e];

    int i1 = 0; float v1 = v[0];
#pragma unroll
    for (int e = 1; e < NE; ++e) if (v[e] > v1) { v1 = v[e]; i1 = e; }
    int i2 = -1; float v2 = -1e30f;
#pragma unroll
    for (int e = 0; e < NE; ++e) if (e != i1 && v[e] > v2) { v2 = v[e]; i2 = e; }

    float s = v1 + v2 + 1e-10f;
    float g1 = v1 / s, g2 = v2 / s;

#pragma unroll
    for (int e = 0; e < NE; ++e) {
        float gv = 0.f;
        if (e == i1) gv = g1;
        if (e == i2) gv = g2;
        g_out[n * NE + e] = gv;
    }
    tke[n * 2 + 0] = i1; tkg[n * 2 + 0] = g1;
    tke[n * 2 + 1] = i2; tkg[n * 2 + 1] = g2;

    int s1 = atomicAdd(&counts[i1], 1);
    bucket[i1 * NTOK + s1] = n * 2 + 0;
    int s2 = atomicAdd(&counts[i2], 1);
    bucket[i2 * NTOK + s2] = n * 2 + 1;
}

// ---------------------------------------------------------------------------
// Grouped bf16 MFMA GEMM (R5-proven config). 128x128x32 tile, 4 waves (2x2 of
// 64x64), dbuf LDS, global_load_lds staging with XOR swizzle via pre-permuted
// source. Grid 1D: e = b&7 (expert pinned to XCD), tile/col from b>>3.
// MODE 1: C = bf16(relu(acc+bias)).  MODE 2: fused relu+dot(W3) -> atomicAdd.
// ---------------------------------------------------------------------------
template<int SHIFT, int MODE>
__global__ __launch_bounds__(256)
void moe_gemm(const ushort* __restrict__ Abf, int lda,
              const ushort* __restrict__ Wt,    // [NE][N][K] bf16
              const float* __restrict__ bias,   // [NE][N]
              int N,
              const float* __restrict__ W3,     // MODE2: [NE][H2D]
              ushort* __restrict__ Cbf,         // MODE1: [NTOK*KSEL][N]
              float* __restrict__ ppart,        // MODE2: [NTOK*KSEL]
              const int* __restrict__ bucket,
              const int* __restrict__ counts,
              int K)
{
    const int b    = blockIdx.x;
    const int e    = b & 7;
    const int idx  = b >> 3;
    const int tile = idx & (MAX_TILES - 1);
    const int col0 = (idx / MAX_TILES) * BN;

    const int cnt  = counts[e];
    const int row0 = tile * BM;
    if (row0 >= cnt) return;

    __shared__ int rowmap[BM];
    __shared__ __align__(16) ushort smA[2][BM * BK];
    __shared__ __align__(16) ushort smB[2][BN * BK];

    const int tid = threadIdx.x;
    if (tid < BM) {
        int r = row0 + tid;
        rowmap[tid] = (r < cnt) ? bucket[e * NTOK + r] : -1;
    }
    __syncthreads();

    const int lane = tid & 63;
    const int wid  = tid >> 6;
    const int wm   = wid >> 1;
    const int wn   = wid & 1;

    const ushort* aSrc[2];
    const ushort* bSrc[2];
    int dstOff[2];
#pragma unroll
    for (int i = 0; i < 2; ++i) {
        int c    = (wid * 2 + i) * 64 + lane;
        int line = c >> 2;
        int slot = c & 3;
        int sch  = slot ^ ((line >> 1) & 3);
        dstOff[i] = c * 8;
        int entry = rowmap[line];
        int arow  = (entry >= 0) ? (entry >> SHIFT) : 0;
        aSrc[i] = Abf + (size_t)arow * lda + sch * 8;
        bSrc[i] = Wt + ((size_t)e * N + col0 + line) * K + sch * 8;
    }

    f32x4 acc[4][4];
#pragma unroll
    for (int i = 0; i < 4; ++i)
#pragma unroll
        for (int j = 0; j < 4; ++j)
            acc[i][j] = (f32x4){0.f, 0.f, 0.f, 0.f};

    auto stage = [&](int buf, int k0) {
#pragma unroll
        for (int i = 0; i < 2; ++i)
            __builtin_amdgcn_global_load_lds(
                (const __attribute__((address_space(1))) unsigned*)(aSrc[i] + k0),
                (__attribute__((address_space(3))) unsigned*)&smA[buf][dstOff[i]],
                16, 0, 0);
#pragma unroll
        for (int i = 0; i < 2; ++i)
            __builtin_amdgcn_global_load_lds(
                (const __attribute__((address_space(1))) unsigned*)(bSrc[i] + k0),
                (__attribute__((address_space(3))) unsigned*)&smB[buf][dstOff[i]],
                16, 0, 0);
    };

    auto compute = [&](int buf) {
        bf16x8 a[4], bfr[4];
#pragma unroll
        for (int mi = 0; mi < 4; ++mi) {
            int row  = wm * 64 + mi * 16 + (lane & 15);
            int slot = (lane >> 4) ^ ((row >> 1) & 3);
            a[mi] = *(const bf16x8*)&smA[buf][row * 32 + slot * 8];
        }
#pragma unroll
        for (int ni = 0; ni < 4; ++ni) {
            int col  = wn * 64 + ni * 16 + (lane & 15);
            int slot = (lane >> 4) ^ ((col >> 1) & 3);
            bfr[ni] = *(const bf16x8*)&smB[buf][col * 32 + slot * 8];
        }
#pragma unroll
        for (int mi = 0; mi < 4; ++mi)
#pragma unroll
            for (int ni = 0; ni < 4; ++ni)
                acc[mi][ni] = __builtin_amdgcn_mfma_f32_16x16x32_bf16(
                    a[mi], bfr[ni], acc[mi][ni], 0, 0, 0);
    };

    const int nt = K / BK;
    stage(0, 0);
    __syncthreads();
    for (int t = 0; t < nt; ++t) {
        int cur = t & 1;
        if (t + 1 < nt) stage(cur ^ 1, (t + 1) * BK);
        compute(cur);
        __syncthreads();
    }

    // ---- epilogue. C/D layout: col=lane&15, row=(lane>>4)*4+reg
    if (MODE == 1) {
        float bb[4];
#pragma unroll
        for (int ni = 0; ni < 4; ++ni)
            bb[ni] = bias[e * N + col0 + wn * 64 + ni * 16 + (lane & 15)];
#pragma unroll
        for (int mi = 0; mi < 4; ++mi) {
#pragma unroll
            for (int r = 0; r < 4; ++r) {
                int rt = wm * 64 + mi * 16 + (lane >> 4) * 4 + r;
                int entry = rowmap[rt];
                if (entry < 0) continue;
                ushort* crow = Cbf + (size_t)entry * N + col0;
#pragma unroll
                for (int ni = 0; ni < 4; ++ni) {
                    float val = fmaxf(acc[mi][ni][r] + bb[ni], 0.f);
                    crow[wn * 64 + ni * 16 + (lane & 15)] = f2bf(val);
                }
            }
        }
    } else {
        float bb[4], w3l[4];
#pragma unroll
        for (int ni = 0; ni < 4; ++ni) {
            int cg = col0 + wn * 64 + ni * 16 + (lane & 15);
            bb[ni]  = bias[e * N + cg];
            w3l[ni] = W3[e * H2D + cg];
        }
#pragma unroll
        for (int mi = 0; mi < 4; ++mi) {
#pragma unroll
            for (int r = 0; r < 4; ++r) {
                float s = 0.f;
#pragma unroll
                for (int ni = 0; ni < 4; ++ni)
                    s += fmaxf(acc[mi][ni][r] + bb[ni], 0.f) * w3l[ni];
#pragma unroll
                for (int off = 1; off < 16; off <<= 1)
                    s += __shfl_xor(s, off, 16);
                if ((lane & 15) == 0) {
                    int rt = wm * 64 + mi * 16 + (lane >> 4) * 4 + r;
                    int entry = rowmap[rt];
                    if (entry >= 0) atomicAdd(&ppart[entry], s);
                }
            }
        }
    }
}

// ---------------------------------------------------------------------------
__global__ void finalize(const float* __restrict__ pp, const float* __restrict__ b3,
                         const int* __restrict__ tke, const float* __restrict__ tkg,
                         float* __restrict__ pred) {
    int n = blockIdx.x * blockDim.x + threadIdx.x;
    if (n >= NTOK) return;
    float r = 0.f;
#pragma unroll
    for (int k = 0; k < KSEL; ++k) {
        int p = n * 2 + k;
        int ee = tke[p];
        float y = 1.f / (1.f + expf(-(pp[p] + b3[ee])));
        r += tkg[p] * y;
    }
    pred[n] = r;
}

// ---------------------------------------------------------------------------
extern "C" void kernel_launch(void* const* d_in, const int* in_sizes, int n_in,
                              void* d_out, int out_size, void* d_ws, size_t ws_size,
                              hipStream_t stream)
{
    const float* x     = (const float*)d_in[0];
    const float* gates = (const float*)d_in[1];
    const float* W1    = (const float*)d_in[2];
    const float* b1    = (const float*)d_in[3];
    const float* W2    = (const float*)d_in[4];
    const float* b2    = (const float*)d_in[5];
    const float* W3    = (const float*)d_in[6];
    const float* b3    = (const float*)d_in[7];

    float* out  = (float*)d_out;
    float* pred = out;
    float* gout = out + NTOK;

    // ws (~73 MB): hdr 1MB | xbf 8MB | h1bf 32MB | Wtbuf 32MB (shared W1t/W2t)
    char* ws = (char*)d_ws;
    int*    counts = (int*)(ws);
    int*    bucket = (int*)(ws + 4096);
    int*    tke    = (int*)(ws + 4096 + 131072);
    float*  tkg    = (float*)(ws + 4096 + 131072 + 32768);
    float*  ppart  = (float*)(ws + 4096 + 131072 + 65536);
    ushort* xbf    = (ushort*)(ws + (1 << 20));
    ushort* h1bf   = (ushort*)(ws + (1 << 20) + (size_t)NTOK * DIN * 2);
    ushort* wtbuf  = (ushort*)(ws + (1 << 20) + (size_t)NTOK * DIN * 2
                                  + (size_t)NTOK * KSEL * H1D * 2);

    // 1) zero counts + x->bf16 + W1 transpose/cvt
    prep1<<<4096, 256, 0, stream>>>(x, xbf, W1, wtbuf, counts);
    // 2) gating (+ ppart zero)
    topk_gate<<<NTOK / 256, 256, 0, stream>>>(gates, gout, counts, bucket,
                                              tke, tkg, ppart);
    // 3) layer 1 GEMM
    moe_gemm<1, 1><<<NE * (H1D / BN) * MAX_TILES, 256, 0, stream>>>(
        xbf, DIN, wtbuf, b1, H1D, nullptr, h1bf, nullptr, bucket, counts, DIN);
    // 4) W2 transpose/cvt (reuses wtbuf after GEMM1)
    prep2<<<2048, 256, 0, stream>>>(W2, wtbuf);
    // 5) layer 2 GEMM + fused layer 3
    moe_gemm<0, 2><<<NE * (H2D / BN) * MAX_TILES, 256, 0, stream>>>(
        h1bf, H1D, wtbuf, b2, H2D, W3, nullptr, ppart, bucket, counts, H1D);
    // 6) sigmoid + gated combine
    finalize<<<NTOK / 256, 256, 0, stream>>>(ppart, b3, tke, tkg, pred);
}